// Round 8
// baseline (176.385 us; speedup 1.0000x reference)
//
#include <hip/hip_runtime.h>
#include <hip/hip_bf16.h>

#define D_MODEL 1024
#define NHEADS  16
#define HD      64
#define BATCH   2
#define SEQ     2048
#define MROWS   4096
#define NQKV    1152    // 1024 Q | 64 K | 64 V
#define NSPLIT  2

typedef short  short4v __attribute__((ext_vector_type(4)));
typedef short  short8  __attribute__((ext_vector_type(8)));
typedef float  floatx4 __attribute__((ext_vector_type(4)));
typedef unsigned uint4v __attribute__((ext_vector_type(4)));

// fp32 -> bf16 (RNE)
__device__ inline short f2bf(float f) {
  unsigned u = __builtin_bit_cast(unsigned, f);
  u = (u + 0x7FFF + ((u >> 16) & 1)) >> 16;
  return (short)u;
}

// pack two f32 -> dword of two bf16 (truncation) in ONE v_perm_b32
__device__ inline unsigned pack_trunc(float lo, float hi) {
  return __builtin_amdgcn_perm(__builtin_bit_cast(unsigned, hi),
                               __builtin_bit_cast(unsigned, lo), 0x07060302u);
}

// async 16B global -> LDS (lds base wave-uniform; HW adds lane*16)
__device__ inline void async_copy16(const short* g, short* l) {
  __builtin_amdgcn_global_load_lds(
      (const __attribute__((address_space(1))) unsigned int*)g,
      (__attribute__((address_space(3))) unsigned int*)l, 16, 0, 0);
}

// ---------------------------------------------------------------------------
// Mega prep: weight transposes (bf16 B^T pack), bias pack, x -> bf16
// ---------------------------------------------------------------------------
__global__ __launch_bounds__(256)
void prep_kernel(const float* __restrict__ x,  const float* __restrict__ Wq,
                 const float* __restrict__ Wk, const float* __restrict__ Wv,
                 const float* __restrict__ Wo, const float* __restrict__ bq,
                 const float* __restrict__ bk, const float* __restrict__ bv,
                 short* __restrict__ xb, short* __restrict__ Wqkv_t,
                 short* __restrict__ Wo_t, float* __restrict__ bqkv) {
  const int id = blockIdx.x;
  const int t  = threadIdx.x;
  if (id < 544) {
    __shared__ short Ts[64 * 72];
    const float* src; short* dst; int N, off, tile;
    if (id < 256)      { src = Wq; dst = Wqkv_t; N = 1024; off = 0;    tile = id; }
    else if (id < 272) { src = Wk; dst = Wqkv_t; N = 64;   off = 1024; tile = id - 256; }
    else if (id < 288) { src = Wv; dst = Wqkv_t; N = 64;   off = 1088; tile = id - 272; }
    else               { src = Wo; dst = Wo_t;   N = 1024; off = 0;    tile = id - 288; }
    const int k0 = (N == 1024) ? (tile & 15) * 64 : tile * 64;
    const int n0 = (N == 1024) ? (tile >> 4) * 64 : 0;
    {
      const int r = t >> 2, c = (t & 3) * 16;
      const float* s = src + (size_t)(k0 + r) * N + n0 + c;
#pragma unroll
      for (int j = 0; j < 16; j += 4) {
        float4 v = *reinterpret_cast<const float4*>(s + j);
        Ts[r * 72 + c + j + 0] = f2bf(v.x); Ts[r * 72 + c + j + 1] = f2bf(v.y);
        Ts[r * 72 + c + j + 2] = f2bf(v.z); Ts[r * 72 + c + j + 3] = f2bf(v.w);
      }
    }
    __syncthreads();
    {
      const int n = t >> 2, kc = (t & 3) * 16;
      short8 o0, o1;
#pragma unroll
      for (int j = 0; j < 8; ++j) o0[j] = Ts[(kc + j) * 72 + n];
#pragma unroll
      for (int j = 0; j < 8; ++j) o1[j] = Ts[(kc + 8 + j) * 72 + n];
      short* d = dst + (size_t)(off + n0 + n) * 1024 + k0 + kc;
      *reinterpret_cast<short8*>(d)     = o0;
      *reinterpret_cast<short8*>(d + 8) = o1;
    }
  } else if (id < 549) {
    const int i = (id - 544) * 256 + t;
    if (i < 1024)      bqkv[i] = bq[i];
    else if (i < 1088) bqkv[i] = bk[i - 1024];
    else if (i < 1152) bqkv[i] = bv[i - 1088];
  } else {
    const int i = ((id - 549) * 256 + t) * 8;
    if (i < MROWS * D_MODEL) {
      float4 a = *reinterpret_cast<const float4*>(x + i);
      float4 b = *reinterpret_cast<const float4*>(x + i + 4);
      short8 o;
      o[0] = f2bf(a.x); o[1] = f2bf(a.y); o[2] = f2bf(a.z); o[3] = f2bf(a.w);
      o[4] = f2bf(b.x); o[5] = f2bf(b.y); o[6] = f2bf(b.z); o[7] = f2bf(b.w);
      *reinterpret_cast<short8*>(xb + i) = o;
    }
  }
}

// ---------------------------------------------------------------------------
// bf16 MFMA GEMM, 128x128 tile, 512 threads / 8 waves (2M x 4N), BK=64,
// PING-PONG double-buffered staging (R5-proven sync): one s_barrier per
// K-step, next step's global_load_lds issued under current compute, vmcnt(0)
// only at loop top. FLOP/staged-byte = 64 (was 42.7 at 128x64) — m93/m230
// shape class, 520-680 TF refcheck'd in the ladder.
// LDS 64 KB -> 2 blocks/CU; Wo grid 32x8=256 blocks (exactly 1/CU, m201
// shape); QKV 32x9=288 (32-block tail accepted).
// SCALE_N: cols < SCALE_N scaled by 0.125*log2(e) (folds attention scale).
// VT_FUSE: cols in [1088,1152) additionally written transposed to Vtg.
// ---------------------------------------------------------------------------
template<bool OUT_BF16, int SCALE_N, bool VT_FUSE>
__global__ __launch_bounds__(512)
void gemm_mfma_bt(const short* __restrict__ A, const short* __restrict__ Bt,
                  const float* __restrict__ bias, void* __restrict__ Cout,
                  short* __restrict__ Vtg, int M, int N, int K) {
  __shared__ short As[2][128 * 64];   // 2 x 16 KB
  __shared__ short Bs[2][128 * 64];   // 2 x 16 KB  (total 64 KB -> 2/CU)
  const int t    = threadIdx.x;
  const int w    = t >> 6;            // 0..7
  const int lane = t & 63;
  const int quad = lane >> 4;
  const int l16  = lane & 15;
  const int bm   = blockIdx.x * 128;
  const int bn   = blockIdx.y * 128;
  const int wm   = (w >> 2) * 64;     // 2 M-halves
  const int wn   = (w & 3) * 32;      // 4 N-quarters

  const int srow = t >> 3;            // 0..63
  const int cc   = ((t & 7) ^ (srow & 7)) * 8;
  const short* gA = A  + (size_t)(bm + srow) * K + cc;
  const short* gB = Bt + (size_t)(bn + srow) * K + cc;

  floatx4 acc[4][2];
#pragma unroll
  for (int i = 0; i < 4; ++i)
#pragma unroll
    for (int j = 0; j < 2; ++j) acc[i][j] = (floatx4){0.f, 0.f, 0.f, 0.f};

  const int xr = l16 & 7;

  // prologue: stage K-step 0 into buffer 0 (512 thr x 16B = 8 KB per copy)
  async_copy16(gA, &As[0][t * 8]);
  async_copy16(gA + (size_t)64 * K, &As[0][t * 8 + 4096]);
  async_copy16(gB, &Bs[0][t * 8]);
  async_copy16(gB + (size_t)64 * K, &Bs[0][t * 8 + 4096]);

  int cur = 0;
  for (int k0 = 0; k0 < K; k0 += 64) {
    // buf[cur]'s DMA (issued last iter, hidden under last compute) must land
    asm volatile("s_waitcnt vmcnt(0)" ::: "memory");
    __builtin_amdgcn_s_barrier();
    __builtin_amdgcn_sched_barrier(0);

    // prefetch next K-step into the other buffer (all waves' reads of it
    // completed before they arrived at the barrier above)
    if (k0 + 64 < K) {
      const int nb = cur ^ 1;
      const int kn = k0 + 64;
      async_copy16(gA + kn, &As[nb][t * 8]);
      async_copy16(gA + (size_t)64 * K + kn, &As[nb][t * 8 + 4096]);
      async_copy16(gB + kn, &Bs[nb][t * 8]);
      async_copy16(gB + (size_t)64 * K + kn, &Bs[nb][t * 8 + 4096]);
    }
    __builtin_amdgcn_sched_barrier(0);   // pin prefetch issue before compute

    const short* Ac = As[cur];
    const short* Bc = Bs[cur];
    short8 fa0[4], fa1[4], fb0[2], fb1[2];
#pragma unroll
    for (int mi = 0; mi < 4; ++mi) {
      const int row = wm + mi * 16 + l16;
      fa0[mi] = *reinterpret_cast<const short8*>(&Ac[row * 64 + (quad ^ xr) * 8]);
      fa1[mi] = *reinterpret_cast<const short8*>(&Ac[row * 64 + ((4 + quad) ^ xr) * 8]);
    }
#pragma unroll
    for (int ni = 0; ni < 2; ++ni) {
      const int row = wn + ni * 16 + l16;
      fb0[ni] = *reinterpret_cast<const short8*>(&Bc[row * 64 + (quad ^ xr) * 8]);
      fb1[ni] = *reinterpret_cast<const short8*>(&Bc[row * 64 + ((4 + quad) ^ xr) * 8]);
    }
    // no explicit lgkmcnt fence: compiler emits fine-grained waits per use
#pragma unroll
    for (int mi = 0; mi < 4; ++mi)
#pragma unroll
      for (int ni = 0; ni < 2; ++ni) {
        acc[mi][ni] = __builtin_amdgcn_mfma_f32_16x16x32_bf16(fa0[mi], fb0[ni], acc[mi][ni], 0, 0, 0);
        acc[mi][ni] = __builtin_amdgcn_mfma_f32_16x16x32_bf16(fa1[mi], fb1[ni], acc[mi][ni], 0, 0, 0);
      }
    cur ^= 1;
  }

#pragma unroll
  for (int ni = 0; ni < 2; ++ni) {
    const int col = bn + wn + ni * 16 + l16;
    const float bs = bias[col];
    const float sc = (col < SCALE_N) ? 0.18033688f : 1.0f;  // 0.125*log2(e)
#pragma unroll
    for (int mi = 0; mi < 4; ++mi) {
      const int row = bm + wm + mi * 16 + quad * 4;
      short4v vt4;
#pragma unroll
      for (int r = 0; r < 4; ++r) {
        const float v = (acc[mi][ni][r] + bs) * sc;
        if (OUT_BF16) {
          const short bv16 = f2bf(v);
          ((short*)Cout)[(size_t)(row + r) * N + col] = bv16;
          if (VT_FUSE) vt4[r] = bv16;
        } else {
          ((float*)Cout)[(size_t)(row + r) * N + col] = v;
        }
      }
      if (VT_FUSE && col >= 1088) {
        const int d = col - 1088;
        const int b = row >> 11, s = row & 2047;
        *reinterpret_cast<short4v*>(&Vtg[(size_t)(b * 64 + d) * SEQ + s]) = vt4;
      }
    }
  }
}

// ---------------------------------------------------------------------------
// bf16 flash MQA — in-register P, QBLK=128 (R5 best build, frozen: five
// structural variants R3-R7 all land 56-59 us -> 2-phase structural floor).
//  - K rows PERMUTED at staging: LDS K row r holds key
//      key(r) = ((r>>4)&1)*4 + ((r>>5)&1)*32 + ((r>>2)&3)*8 + (r&3)
//    -> QK^T output lane (l16,quad) holds exactly keys quad*8..quad*8+7:
//    the PV A-fragment is LANE-LOCAL, P never touches LDS.
//  - two 16KB KV half-buffers, ping-pong; one s_barrier per 64-key tile,
//    prefetch issued under compute, no exposed drain
//  - NSPLIT=2 via grid.z; partials O fp16 / l fp32 (exact combine)
//  - __launch_bounds__(256,3): (256,4) forced 128-VGPR cap and spilled (R1).
// ---------------------------------------------------------------------------
__global__ __launch_bounds__(256, 3)
void mqa_flash_bf16(const short* __restrict__ QKV, const short* __restrict__ Vtg,
                    _Float16* __restrict__ Opart, float* __restrict__ lpart) {
  const int bh    = blockIdx.y;
  const int b     = bh >> 4;
  const int h     = bh & 15;
  const int s0    = blockIdx.x * 128;
  const int split = blockIdx.z;
  const int t     = threadIdx.x;
  const int w     = t >> 6;
  const int lane  = t & 63;
  const int quad  = lane >> 4;
  const int l16   = lane & 15;

  __shared__ short KVs[16384];        // buf0: K[0,4K) V[4K,8K) | buf1: +8192

  // Q B-frags (pre-scaled in GEMM epilogue)
  short8 aq[2][2];
#pragma unroll
  for (int st = 0; st < 2; ++st) {
    const short* qrow = &QKV[(size_t)(b * SEQ + s0 + w * 32 + st * 16 + l16) * NQKV + h * HD];
    aq[st][0] = *reinterpret_cast<const short8*>(qrow + quad * 8);
    aq[st][1] = *reinterpret_cast<const short8*>(qrow + 32 + quad * 8);
  }

  floatx4 oacc[2][4];
  floatx4 lacc[2];
#pragma unroll
  for (int st = 0; st < 2; ++st) {
    lacc[st] = (floatx4){0.f, 0.f, 0.f, 0.f};
#pragma unroll
    for (int dg = 0; dg < 4; ++dg) oacc[st][dg] = (floatx4){0.f, 0.f, 0.f, 0.f};
  }

  short8 ones;
#pragma unroll
  for (int j = 0; j < 8; ++j) ones[j] = (short)0x3F80;  // bf16 1.0

  // staging source (XOR-swizzled chunks). K source row is the PERMUTED key
  // row key(srow); key(srow+32) = key(srow)+32 keeps the +32*NQKV offset.
  const int srow  = t >> 3;                        // 0..31 (LDS row)
  const int cc    = ((t & 7) ^ (srow & 7)) * 8;
  const int krow  = ((srow >> 4) & 1) * 4 + ((srow >> 2) & 3) * 8 + (srow & 3);
  const int kbase = split * (SEQ / NSPLIT);
  const short* gK = QKV + (size_t)(b * SEQ + kbase + krow) * NQKV + 1024 + cc;
  const short* gV = Vtg + (size_t)(b * 64 + srow) * SEQ + kbase + cc;
  short* lK = KVs + w * 512;          // rows srow (+32 rows at +2048 shorts)
  short* lV = KVs + 4096 + w * 512;

  const int xr = l16 & 7;

  // prologue: stage tile 0 into buf0
  async_copy16(gK, lK);
  async_copy16(gK + (size_t)32 * NQKV, lK + 2048);
  async_copy16(gV, lV);
  async_copy16(gV + (size_t)32 * SEQ, lV + 2048);
  gK += (size_t)64 * NQKV;
  gV += 64;

  const int NT = (SEQ / NSPLIT) / 64;   // 16 tiles
  int cur = 0;

  for (int it = 0; it < NT; ++it) {
    // buf[cur]'s DMA (issued last iter, hidden under last compute) must land
    asm volatile("s_waitcnt vmcnt(0)" ::: "memory");
    __builtin_amdgcn_s_barrier();
    __builtin_amdgcn_sched_barrier(0);

    // prefetch next tile into the other buffer (all waves' reads of that
    // buffer completed before they arrived at the barrier above)
    if (it + 1 < NT) {
      const int nb = (cur ^ 1) * 8192;
      async_copy16(gK, lK + nb);
      async_copy16(gK + (size_t)32 * NQKV, lK + nb + 2048);
      async_copy16(gV, lV + nb);
      async_copy16(gV + (size_t)32 * SEQ, lV + nb + 2048);
      gK += (size_t)64 * NQKV;
      gV += 64;
    }
    __builtin_amdgcn_sched_barrier(0);   // pin prefetch issue before compute

    const short* Ks = KVs + cur * 8192;
    const short* Vt = Ks + 4096;

    // K A-frags + V B-frags (XOR-swizzled reads); compiler inserts
    // fine-grained lgkmcnt per consuming MFMA (no full-drain fence)
    short8 kb[4][2], vb[4][2];
#pragma unroll
    for (int kg = 0; kg < 4; ++kg) {
      kb[kg][0] = *reinterpret_cast<const short8*>(&Ks[(kg * 16 + l16) * 64 + (quad ^ xr) * 8]);
      kb[kg][1] = *reinterpret_cast<const short8*>(&Ks[(kg * 16 + l16) * 64 + ((4 + quad) ^ xr) * 8]);
    }
#pragma unroll
    for (int dg = 0; dg < 4; ++dg) {
      vb[dg][0] = *reinterpret_cast<const short8*>(&Vt[(dg * 16 + l16) * 64 + (quad ^ xr) * 8]);
      vb[dg][1] = *reinterpret_cast<const short8*>(&Vt[(dg * 16 + l16) * 64 + ((4 + quad) ^ xr) * 8]);
    }

#pragma unroll
    for (int st = 0; st < 2; ++st) {
      // S^T = K·Q^T over permuted key rows; p = exp2(s)
      floatx4 s4[4];
#pragma unroll
      for (int kg = 0; kg < 4; ++kg) {
        s4[kg] = (floatx4){0.f, 0.f, 0.f, 0.f};
        s4[kg] = __builtin_amdgcn_mfma_f32_16x16x32_bf16(kb[kg][0], aq[st][0], s4[kg], 0, 0, 0);
        s4[kg] = __builtin_amdgcn_mfma_f32_16x16x32_bf16(kb[kg][1], aq[st][1], s4[kg], 0, 0, 0);
      }
      // lane-local P -> bf16 A-frags (key(r) permutation makes lane (l16,quad)
      // hold keys quad*8..+3 (kg even) and quad*8+4..+7 (kg odd))
      unsigned pk[8];
#pragma unroll
      for (int kg = 0; kg < 4; ++kg) {
        const float p0 = __builtin_exp2f(s4[kg][0]);
        const float p1 = __builtin_exp2f(s4[kg][1]);
        const float p2 = __builtin_exp2f(s4[kg][2]);
        const float p3 = __builtin_exp2f(s4[kg][3]);
        pk[kg * 2 + 0] = pack_trunc(p0, p1);
        pk[kg * 2 + 1] = pack_trunc(p2, p3);
      }
      const uint4v u0 = (uint4v){pk[0], pk[1], pk[2], pk[3]};
      const uint4v u1 = (uint4v){pk[4], pk[5], pk[6], pk[7]};
      const short8 ap0 = __builtin_bit_cast(short8, u0);
      const short8 ap1 = __builtin_bit_cast(short8, u1);

      // O += P·V ; l += P·ones
      __builtin_amdgcn_s_setprio(1);
      lacc[st] = __builtin_amdgcn_mfma_f32_16x16x32_bf16(ap0, ones, lacc[st], 0, 0, 0);
      lacc[st] = __builtin_amdgcn_mfma_f32_16x16x32_bf16(ap1, ones, lacc[st], 0, 0, 0);
#pragma unroll
      for (int dg = 0; dg < 4; ++dg) {
        oacc[st][dg] = __builtin_amdgcn_mfma_f32_16x16x32_bf16(ap0, vb[dg][0], oacc[st][dg], 0, 0, 0);
        oacc[st][dg] = __builtin_amdgcn_mfma_f32_16x16x32_bf16(ap1, vb[dg][1], oacc[st][dg], 0, 0, 0);
      }
      __builtin_amdgcn_s_setprio(0);
    }
    cur ^= 1;
  }

  // partial epilogue: fp16 O, fp32 l
#pragma unroll
  for (int st = 0; st < 2; ++st) {
#pragma unroll
    for (int rg = 0; rg < 4; ++rg) {
      const int qg = s0 + w * 32 + st * 16 + quad * 4 + rg;
      _Float16* dst = Opart + ((size_t)(split * 32 + bh) * SEQ + qg) * 64 + l16;
#pragma unroll
      for (int dg = 0; dg < 4; ++dg) dst[dg * 16] = (_Float16)oacc[st][dg][rg];
      if (l16 == 0) lpart[(size_t)(split * 32 + bh) * SEQ + qg] = lacc[st][rg];
    }
  }
}

// ---------------------------------------------------------------------------
// combine: Att[b*S+q][h*64+d] = (sum_s O_s)/(sum_s l_s), bf16 out
// ---------------------------------------------------------------------------
__global__ __launch_bounds__(256)
void combine_kernel(const _Float16* __restrict__ Opart, const float* __restrict__ lpart,
                    short* __restrict__ Att) {
  const int idx = blockIdx.x * 256 + threadIdx.x;   // 524288 total
  const int r   = idx >> 3;                          // bh*2048 + q
  const int d0  = (idx & 7) * 8;
  float l = 0.f;
  float o[8] = {0.f,0.f,0.f,0.f,0.f,0.f,0.f,0.f};
#pragma unroll
  for (int s = 0; s < NSPLIT; ++s) {
    const _Float16* op = Opart + ((size_t)(s * 32 * SEQ) + r) * 64 + d0;
    l += lpart[(size_t)s * 32 * SEQ + r];
#pragma unroll
    for (int j = 0; j < 8; ++j) o[j] += (float)op[j];
  }
  const float inv = 1.0f / l;
  short8 ov;
#pragma unroll
  for (int j = 0; j < 8; ++j) ov[j] = f2bf(o[j] * inv);
  const int bhh = r >> 11, q = r & 2047;
  const int bb = bhh >> 4, hh = bhh & 15;
  *reinterpret_cast<short8*>(&Att[(size_t)(bb * SEQ + q) * D_MODEL + hh * HD + d0]) = ov;
}

// ---------------------------------------------------------------------------
extern "C" void kernel_launch(void* const* d_in, const int* in_sizes, int n_in,
                              void* d_out, int out_size, void* d_ws, size_t ws_size,
                              hipStream_t stream) {
  const float* x  = (const float*)d_in[0];
  const float* Wq = (const float*)d_in[1];
  const float* bq = (const float*)d_in[2];
  const float* Wk = (const float*)d_in[3];
  const float* bk = (const float*)d_in[4];
  const float* Wv = (const float*)d_in[5];
  const float* bv = (const float*)d_in[6];
  const float* Wo = (const float*)d_in[7];
  const float* bo = (const float*)d_in[8];
  float* out = (float*)d_out;

  short* Wqkv_t = (short*)d_ws;                              // 1152*1024
  short* Wo_t   = Wqkv_t + (size_t)NQKV * D_MODEL;           // 1024*1024
  short* xb     = Wo_t + (size_t)D_MODEL * D_MODEL;          // 4096*1024
  short* QKV    = xb + (size_t)MROWS * D_MODEL;              // 4096*1152
  short* Att    = QKV + (size_t)MROWS * NQKV;                // 4096*1024
  short* Vtg    = Att + (size_t)MROWS * D_MODEL;             // 2*64*2048
  float* bqkv   = (float*)(Vtg + (size_t)BATCH * HD * SEQ);  // 1152
  float* lpart  = bqkv + 1152;                               // NSPLIT*32*2048
  _Float16* Opart = (_Float16*)(lpart + (size_t)NSPLIT * 32 * SEQ);  // NSPLIT*32*2048*64

  prep_kernel<<<2597, 256, 0, stream>>>(x, Wq, Wk, Wv, Wo, bq, bk, bv,
                                        xb, Wqkv_t, Wo_t, bqkv);

  // QKV projection; Q cols pre-scaled; V cols also written transposed (Vtg)
  gemm_mfma_bt<true, 1024, true><<<dim3(MROWS / 128, NQKV / 128), 512, 0, stream>>>(
      xb, Wqkv_t, bqkv, QKV, Vtg, MROWS, NQKV, D_MODEL);

  mqa_flash_bf16<<<dim3(SEQ / 128, BATCH * NHEADS, NSPLIT), 256, 0, stream>>>(
      QKV, Vtg, Opart, lpart);

  combine_kernel<<<2048, 256, 0, stream>>>(Opart, lpart, Att);

  gemm_mfma_bt<false, 0, false><<<dim3(MROWS / 128, D_MODEL / 128), 512, 0, stream>>>(
      Att, Wo_t, bo, out, nullptr, MROWS, D_MODEL, D_MODEL);
}

// Round 9
// 167.927 us; speedup vs baseline: 1.0504x; 1.0504x over previous
//
#include <hip/hip_runtime.h>
#include <hip/hip_bf16.h>

#define D_MODEL 1024
#define NHEADS  16
#define HD      64
#define BATCH   2
#define SEQ     2048
#define MROWS   4096
#define NQKV    1152    // 1024 Q | 64 K | 64 V

typedef short  short4v __attribute__((ext_vector_type(4)));
typedef short  short8  __attribute__((ext_vector_type(8)));
typedef float  floatx4 __attribute__((ext_vector_type(4)));
typedef unsigned uint4v __attribute__((ext_vector_type(4)));

// fp32 -> bf16 (RNE)
__device__ inline short f2bf(float f) {
  unsigned u = __builtin_bit_cast(unsigned, f);
  u = (u + 0x7FFF + ((u >> 16) & 1)) >> 16;
  return (short)u;
}

// pack two f32 -> dword of two bf16 (truncation) in ONE v_perm_b32
__device__ inline unsigned pack_trunc(float lo, float hi) {
  return __builtin_amdgcn_perm(__builtin_bit_cast(unsigned, hi),
                               __builtin_bit_cast(unsigned, lo), 0x07060302u);
}

// async 16B global -> LDS (lds base wave-uniform; HW adds lane*16)
__device__ inline void async_copy16(const short* g, short* l) {
  __builtin_amdgcn_global_load_lds(
      (const __attribute__((address_space(1))) unsigned int*)g,
      (__attribute__((address_space(3))) unsigned int*)l, 16, 0, 0);
}

// ---------------------------------------------------------------------------
// Mega prep: weight transposes (bf16 B^T pack), bias pack, x -> bf16
// ---------------------------------------------------------------------------
__global__ __launch_bounds__(256)
void prep_kernel(const float* __restrict__ x,  const float* __restrict__ Wq,
                 const float* __restrict__ Wk, const float* __restrict__ Wv,
                 const float* __restrict__ Wo, const float* __restrict__ bq,
                 const float* __restrict__ bk, const float* __restrict__ bv,
                 short* __restrict__ xb, short* __restrict__ Wqkv_t,
                 short* __restrict__ Wo_t, float* __restrict__ bqkv) {
  const int id = blockIdx.x;
  const int t  = threadIdx.x;
  if (id < 544) {
    __shared__ short Ts[64 * 72];
    const float* src; short* dst; int N, off, tile;
    if (id < 256)      { src = Wq; dst = Wqkv_t; N = 1024; off = 0;    tile = id; }
    else if (id < 272) { src = Wk; dst = Wqkv_t; N = 64;   off = 1024; tile = id - 256; }
    else if (id < 288) { src = Wv; dst = Wqkv_t; N = 64;   off = 1088; tile = id - 272; }
    else               { src = Wo; dst = Wo_t;   N = 1024; off = 0;    tile = id - 288; }
    const int k0 = (N == 1024) ? (tile & 15) * 64 : tile * 64;
    const int n0 = (N == 1024) ? (tile >> 4) * 64 : 0;
    {
      const int r = t >> 2, c = (t & 3) * 16;
      const float* s = src + (size_t)(k0 + r) * N + n0 + c;
#pragma unroll
      for (int j = 0; j < 16; j += 4) {
        float4 v = *reinterpret_cast<const float4*>(s + j);
        Ts[r * 72 + c + j + 0] = f2bf(v.x); Ts[r * 72 + c + j + 1] = f2bf(v.y);
        Ts[r * 72 + c + j + 2] = f2bf(v.z); Ts[r * 72 + c + j + 3] = f2bf(v.w);
      }
    }
    __syncthreads();
    {
      const int n = t >> 2, kc = (t & 3) * 16;
      short8 o0, o1;
#pragma unroll
      for (int j = 0; j < 8; ++j) o0[j] = Ts[(kc + j) * 72 + n];
#pragma unroll
      for (int j = 0; j < 8; ++j) o1[j] = Ts[(kc + 8 + j) * 72 + n];
      short* d = dst + (size_t)(off + n0 + n) * 1024 + k0 + kc;
      *reinterpret_cast<short8*>(d)     = o0;
      *reinterpret_cast<short8*>(d + 8) = o1;
    }
  } else if (id < 549) {
    const int i = (id - 544) * 256 + t;
    if (i < 1024)      bqkv[i] = bq[i];
    else if (i < 1088) bqkv[i] = bk[i - 1024];
    else if (i < 1152) bqkv[i] = bv[i - 1088];
  } else {
    const int i = ((id - 549) * 256 + t) * 8;
    if (i < MROWS * D_MODEL) {
      float4 a = *reinterpret_cast<const float4*>(x + i);
      float4 b = *reinterpret_cast<const float4*>(x + i + 4);
      short8 o;
      o[0] = f2bf(a.x); o[1] = f2bf(a.y); o[2] = f2bf(a.z); o[3] = f2bf(a.w);
      o[4] = f2bf(b.x); o[5] = f2bf(b.y); o[6] = f2bf(b.z); o[7] = f2bf(b.w);
      *reinterpret_cast<short8*>(xb + i) = o;
    }
  }
}

// ---------------------------------------------------------------------------
// bf16 MFMA GEMM, 128x64 tile, BK=64, PING-PONG double-buffered staging
// (R5 build — best measured; 128x128/512thr was slower, R8).
// SCALE_N: cols < SCALE_N scaled by 0.125*log2(e) (folds attention scale).
// VT_FUSE: cols in [1088,1152) additionally written transposed to Vtg.
// ---------------------------------------------------------------------------
template<bool OUT_BF16, int SCALE_N, bool VT_FUSE>
__global__ __launch_bounds__(256)
void gemm_mfma_bt(const short* __restrict__ A, const short* __restrict__ Bt,
                  const float* __restrict__ bias, void* __restrict__ Cout,
                  short* __restrict__ Vtg, int M, int N, int K) {
  __shared__ short As[2][128 * 64];   // 2 x 16 KB
  __shared__ short Bs[2][64 * 64];    // 2 x  8 KB   (total 48 KB -> 3/CU)
  const int t    = threadIdx.x;
  const int w    = t >> 6;
  const int lane = t & 63;
  const int quad = lane >> 4;
  const int l16  = lane & 15;
  const int bm   = blockIdx.x * 128;
  const int bn   = blockIdx.y * 64;
  const int wm   = (w >> 1) * 64;
  const int wn   = (w & 1) * 32;

  const int srow = t >> 3;
  const int cc   = ((t & 7) ^ (srow & 7)) * 8;
  const short* gA = A  + (size_t)(bm + srow) * K + cc;
  const short* gB = Bt + (size_t)(bn + srow) * K + cc;

  floatx4 acc[4][2];
#pragma unroll
  for (int i = 0; i < 4; ++i)
#pragma unroll
    for (int j = 0; j < 2; ++j) acc[i][j] = (floatx4){0.f, 0.f, 0.f, 0.f};

  const int xr = l16 & 7;

  // prologue: stage K-step 0 into buffer 0
  async_copy16(gA, &As[0][t * 8]);
  async_copy16(gA + (size_t)32 * K, &As[0][t * 8 + 2048]);
  async_copy16(gA + (size_t)64 * K, &As[0][t * 8 + 4096]);
  async_copy16(gA + (size_t)96 * K, &As[0][t * 8 + 6144]);
  async_copy16(gB, &Bs[0][t * 8]);
  async_copy16(gB + (size_t)32 * K, &Bs[0][t * 8 + 2048]);

  int cur = 0;
  for (int k0 = 0; k0 < K; k0 += 64) {
    asm volatile("s_waitcnt vmcnt(0)" ::: "memory");
    __builtin_amdgcn_s_barrier();
    __builtin_amdgcn_sched_barrier(0);

    if (k0 + 64 < K) {
      const int nb = cur ^ 1;
      const int kn = k0 + 64;
      async_copy16(gA + kn, &As[nb][t * 8]);
      async_copy16(gA + (size_t)32 * K + kn, &As[nb][t * 8 + 2048]);
      async_copy16(gA + (size_t)64 * K + kn, &As[nb][t * 8 + 4096]);
      async_copy16(gA + (size_t)96 * K + kn, &As[nb][t * 8 + 6144]);
      async_copy16(gB + kn, &Bs[nb][t * 8]);
      async_copy16(gB + (size_t)32 * K + kn, &Bs[nb][t * 8 + 2048]);
    }
    __builtin_amdgcn_sched_barrier(0);   // pin prefetch issue before compute

    const short* Ac = As[cur];
    const short* Bc = Bs[cur];
    short8 fa0[4], fa1[4], fb0[2], fb1[2];
#pragma unroll
    for (int mi = 0; mi < 4; ++mi) {
      const int row = wm + mi * 16 + l16;
      fa0[mi] = *reinterpret_cast<const short8*>(&Ac[row * 64 + (quad ^ xr) * 8]);
      fa1[mi] = *reinterpret_cast<const short8*>(&Ac[row * 64 + ((4 + quad) ^ xr) * 8]);
    }
#pragma unroll
    for (int ni = 0; ni < 2; ++ni) {
      const int row = wn + ni * 16 + l16;
      fb0[ni] = *reinterpret_cast<const short8*>(&Bc[row * 64 + (quad ^ xr) * 8]);
      fb1[ni] = *reinterpret_cast<const short8*>(&Bc[row * 64 + ((4 + quad) ^ xr) * 8]);
    }
#pragma unroll
    for (int mi = 0; mi < 4; ++mi)
#pragma unroll
      for (int ni = 0; ni < 2; ++ni) {
        acc[mi][ni] = __builtin_amdgcn_mfma_f32_16x16x32_bf16(fa0[mi], fb0[ni], acc[mi][ni], 0, 0, 0);
        acc[mi][ni] = __builtin_amdgcn_mfma_f32_16x16x32_bf16(fa1[mi], fb1[ni], acc[mi][ni], 0, 0, 0);
      }
    cur ^= 1;
  }

#pragma unroll
  for (int ni = 0; ni < 2; ++ni) {
    const int col = bn + wn + ni * 16 + l16;
    const float bs = bias[col];
    const float sc = (col < SCALE_N) ? 0.18033688f : 1.0f;  // 0.125*log2(e)
#pragma unroll
    for (int mi = 0; mi < 4; ++mi) {
      const int row = bm + wm + mi * 16 + quad * 4;
      short4v vt4;
#pragma unroll
      for (int r = 0; r < 4; ++r) {
        const float v = (acc[mi][ni][r] + bs) * sc;
        if (OUT_BF16) {
          const short bv16 = f2bf(v);
          ((short*)Cout)[(size_t)(row + r) * N + col] = bv16;
          if (VT_FUSE) vt4[r] = bv16;
        } else {
          ((float*)Cout)[(size_t)(row + r) * N + col] = v;
        }
      }
      if (VT_FUSE && col >= 1088) {
        const int d = col - 1088;
        const int b = row >> 11, s = row & 2047;
        *reinterpret_cast<short4v*>(&Vtg[(size_t)(b * 64 + d) * SEQ + s]) = vt4;
      }
    }
  }
}

// ---------------------------------------------------------------------------
// bf16 flash MQA — in-register P, QBLK=128, 128-KEY TILES PER BARRIER.
//  Flash was ~45% sync-stalled (per-64-key vmcnt+barrier); this doubles the
//  tile: per buffer K[128][64] (16KB) + V^T[64][128] (16KB), ping-pong 64KB.
//  One vmcnt(0)+s_barrier per 128 keys (half the sync events); per-64-key
//  half compute is identical to the proven R5 tile.
//  - K rows PERMUTED at staging: row r holds key
//      key(r) = (r&96) + ((r>>4)&1)*4 + ((r>>2)&3)*8 + (r&3)
//    -> QK^T output lane (l16,quad) holds keys half*64+quad*8..+7 natural:
//    PV A-fragment is LANE-LOCAL, P never touches LDS.
//  - V^T [64][128] with 16B-chunk XOR swizzle (phys = logical ^ (d&7)):
//    2-way bank aliasing only (free).
//  - 64KB LDS -> 2 blocks/CU; grid 512 = 256 CU x 2 exactly, no split, no
//    combine pass: final softmax divide + bf16 Att written here.
// ---------------------------------------------------------------------------
__global__ __launch_bounds__(256, 2)
void mqa_flash_bf16(const short* __restrict__ QKV, const short* __restrict__ Vtg,
                    short* __restrict__ Att) {
  const int bh   = blockIdx.y;
  const int b    = bh >> 4;
  const int h    = bh & 15;
  const int s0   = blockIdx.x * 128;
  const int t    = threadIdx.x;
  const int w    = t >> 6;
  const int lane = t & 63;
  const int quad = lane >> 4;
  const int l16  = lane & 15;

  __shared__ short KVs[2][16384];   // per buf: K[128][64] @0 | V[64][128] @8192

  // Q B-frags (pre-scaled in GEMM epilogue)
  short8 aq[2][2];
#pragma unroll
  for (int st = 0; st < 2; ++st) {
    const short* qrow = &QKV[(size_t)(b * SEQ + s0 + w * 32 + st * 16 + l16) * NQKV + h * HD];
    aq[st][0] = *reinterpret_cast<const short8*>(qrow + quad * 8);
    aq[st][1] = *reinterpret_cast<const short8*>(qrow + 32 + quad * 8);
  }

  floatx4 oacc[2][4];
  floatx4 lacc[2];
#pragma unroll
  for (int st = 0; st < 2; ++st) {
    lacc[st] = (floatx4){0.f, 0.f, 0.f, 0.f};
#pragma unroll
    for (int dg = 0; dg < 4; ++dg) oacc[st][dg] = (floatx4){0.f, 0.f, 0.f, 0.f};
  }

  short8 ones;
#pragma unroll
  for (int j = 0; j < 8; ++j) ones[j] = (short)0x3F80;  // bf16 1.0

  // K staging source: 32-row groups; permuted key row; XOR-swizzled chunks.
  // key(r+32)=key(r)+32, key(r+64)=key(r)+64 -> uniform +32/64/96*NQKV offs.
  const int srow = t >> 3;                        // 0..31
  const int ccK  = ((t & 7) ^ (srow & 7)) * 8;
  const int krow = ((srow >> 4) & 1) * 4 + ((srow >> 2) & 3) * 8 + (srow & 3);
  const short* gK = QKV + (size_t)(b * SEQ + krow) * NQKV + 1024 + ccK;
  // V staging source: [64][128] rows d=t>>4 per 16-row copy; chunk swizzle.
  const int vrow = t >> 4;                        // 0..15
  const int ccV  = ((t & 15) ^ (vrow & 7)) * 8;
  const short* gV = Vtg + (size_t)(b * 64 + vrow) * SEQ + ccV;

  const int xr = l16 & 7;

#define STAGE(BUF)                                                     \
  {                                                                    \
    short* lK = KVs[BUF] + w * 512;                                    \
    short* lV = KVs[BUF] + 8192 + w * 512;                             \
    async_copy16(gK, lK);                                              \
    async_copy16(gK + (size_t)32 * NQKV, lK + 2048);                   \
    async_copy16(gK + (size_t)64 * NQKV, lK + 4096);                   \
    async_copy16(gK + (size_t)96 * NQKV, lK + 6144);                   \
    async_copy16(gV, lV);                                              \
    async_copy16(gV + (size_t)16 * SEQ, lV + 2048);                    \
    async_copy16(gV + (size_t)32 * SEQ, lV + 4096);                    \
    async_copy16(gV + (size_t)48 * SEQ, lV + 6144);                    \
    gK += (size_t)128 * NQKV;                                          \
    gV += 128;                                                         \
  }

  // prologue: stage tile 0 (128 keys) into buf0
  STAGE(0)

  const int NT = SEQ / 128;   // 16
  int cur = 0;

  for (int it = 0; it < NT; ++it) {
    // buf[cur]'s DMA (issued last iter, hidden under 128 keys of compute)
    asm volatile("s_waitcnt vmcnt(0)" ::: "memory");
    __builtin_amdgcn_s_barrier();
    __builtin_amdgcn_sched_barrier(0);

    // prefetch next 128-key tile into the other buffer (all waves' reads of
    // it completed before they arrived at the barrier above)
    if (it + 1 < NT) STAGE(cur ^ 1)
    __builtin_amdgcn_sched_barrier(0);   // pin prefetch issue before compute

#pragma unroll
    for (int half = 0; half < 2; ++half) {
      const short* Ks = KVs[cur] + half * 4096;   // rows half*64..+63
      const short* Vt = KVs[cur] + 8192;          // [64][128]
      const int vc = half * 8;                    // chunk offset (keys +64)

      short8 kb[4][2], vb[4][2];
#pragma unroll
      for (int kg = 0; kg < 4; ++kg) {
        kb[kg][0] = *reinterpret_cast<const short8*>(&Ks[(kg * 16 + l16) * 64 + (quad ^ xr) * 8]);
        kb[kg][1] = *reinterpret_cast<const short8*>(&Ks[(kg * 16 + l16) * 64 + ((4 + quad) ^ xr) * 8]);
      }
#pragma unroll
      for (int dg = 0; dg < 4; ++dg) {
        vb[dg][0] = *reinterpret_cast<const short8*>(&Vt[(dg * 16 + l16) * 128 + (vc + (quad ^ xr)) * 8]);
        vb[dg][1] = *reinterpret_cast<const short8*>(&Vt[(dg * 16 + l16) * 128 + (vc + ((4 + quad) ^ xr)) * 8]);
      }

#pragma unroll
      for (int st = 0; st < 2; ++st) {
        // S^T = K·Q^T over permuted key rows; p = exp2(s)
        floatx4 s4[4];
#pragma unroll
        for (int kg = 0; kg < 4; ++kg) {
          s4[kg] = (floatx4){0.f, 0.f, 0.f, 0.f};
          s4[kg] = __builtin_amdgcn_mfma_f32_16x16x32_bf16(kb[kg][0], aq[st][0], s4[kg], 0, 0, 0);
          s4[kg] = __builtin_amdgcn_mfma_f32_16x16x32_bf16(kb[kg][1], aq[st][1], s4[kg], 0, 0, 0);
        }
        // lane-local P -> bf16 A-frags (keys quad*8..+7 natural within half)
        unsigned pk[8];
#pragma unroll
        for (int kg = 0; kg < 4; ++kg) {
          const float p0 = __builtin_exp2f(s4[kg][0]);
          const float p1 = __builtin_exp2f(s4[kg][1]);
          const float p2 = __builtin_exp2f(s4[kg][2]);
          const float p3 = __builtin_exp2f(s4[kg][3]);
          pk[kg * 2 + 0] = pack_trunc(p0, p1);
          pk[kg * 2 + 1] = pack_trunc(p2, p3);
        }
        const uint4v u0 = (uint4v){pk[0], pk[1], pk[2], pk[3]};
        const uint4v u1 = (uint4v){pk[4], pk[5], pk[6], pk[7]};
        const short8 ap0 = __builtin_bit_cast(short8, u0);
        const short8 ap1 = __builtin_bit_cast(short8, u1);

        // O += P·V ; l += P·ones
        __builtin_amdgcn_s_setprio(1);
        lacc[st] = __builtin_amdgcn_mfma_f32_16x16x32_bf16(ap0, ones, lacc[st], 0, 0, 0);
        lacc[st] = __builtin_amdgcn_mfma_f32_16x16x32_bf16(ap1, ones, lacc[st], 0, 0, 0);
#pragma unroll
        for (int dg = 0; dg < 4; ++dg) {
          oacc[st][dg] = __builtin_amdgcn_mfma_f32_16x16x32_bf16(ap0, vb[dg][0], oacc[st][dg], 0, 0, 0);
          oacc[st][dg] = __builtin_amdgcn_mfma_f32_16x16x32_bf16(ap1, vb[dg][1], oacc[st][dg], 0, 0, 0);
        }
        __builtin_amdgcn_s_setprio(0);
      }
    }
    cur ^= 1;
  }
#undef STAGE

  // epilogue: final softmax divide, write bf16 Att directly
  short* At = Att + (size_t)b * SEQ * D_MODEL + h * HD;
#pragma unroll
  for (int st = 0; st < 2; ++st) {
#pragma unroll
    for (int rg = 0; rg < 4; ++rg) {
      const int q = s0 + w * 32 + st * 16 + quad * 4 + rg;
      const float inv = 1.0f / lacc[st][rg];
      short* dst = At + (size_t)q * D_MODEL + l16;
#pragma unroll
      for (int dg = 0; dg < 4; ++dg) dst[dg * 16] = f2bf(oacc[st][dg][rg] * inv);
    }
  }
}

// ---------------------------------------------------------------------------
extern "C" void kernel_launch(void* const* d_in, const int* in_sizes, int n_in,
                              void* d_out, int out_size, void* d_ws, size_t ws_size,
                              hipStream_t stream) {
  const float* x  = (const float*)d_in[0];
  const float* Wq = (const float*)d_in[1];
  const float* bq = (const float*)d_in[2];
  const float* Wk = (const float*)d_in[3];
  const float* bk = (const float*)d_in[4];
  const float* Wv = (const float*)d_in[5];
  const float* bv = (const float*)d_in[6];
  const float* Wo = (const float*)d_in[7];
  const float* bo = (const float*)d_in[8];
  float* out = (float*)d_out;

  short* Wqkv_t = (short*)d_ws;                              // 1152*1024
  short* Wo_t   = Wqkv_t + (size_t)NQKV * D_MODEL;           // 1024*1024
  short* xb     = Wo_t + (size_t)D_MODEL * D_MODEL;          // 4096*1024
  short* QKV    = xb + (size_t)MROWS * D_MODEL;              // 4096*1152
  short* Att    = QKV + (size_t)MROWS * NQKV;                // 4096*1024
  short* Vtg    = Att + (size_t)MROWS * D_MODEL;             // 2*64*2048
  float* bqkv   = (float*)(Vtg + (size_t)BATCH * HD * SEQ);  // 1152

  prep_kernel<<<2597, 256, 0, stream>>>(x, Wq, Wk, Wv, Wo, bq, bk, bv,
                                        xb, Wqkv_t, Wo_t, bqkv);

  // QKV projection; Q cols pre-scaled; V cols also written transposed (Vtg)
  gemm_mfma_bt<true, 1024, true><<<dim3(MROWS / 128, NQKV / 64), 256, 0, stream>>>(
      xb, Wqkv_t, bqkv, QKV, Vtg, MROWS, NQKV, D_MODEL);

  mqa_flash_bf16<<<dim3(SEQ / 128, BATCH * NHEADS), 256, 0, stream>>>(
      QKV, Vtg, Att);

  gemm_mfma_bt<false, 0, false><<<dim3(MROWS / 128, D_MODEL / 64), 256, 0, stream>>>(
      Att, Wo_t, bo, out, nullptr, MROWS, D_MODEL, D_MODEL);
}

// Round 10
// 165.658 us; speedup vs baseline: 1.0648x; 1.0137x over previous
//
#include <hip/hip_runtime.h>
#include <hip/hip_bf16.h>

#define D_MODEL 1024
#define NHEADS  16
#define HD      64
#define BATCH   2
#define SEQ     2048
#define MROWS   4096
#define NQKV    1152    // 1024 Q | 64 K | 64 V

typedef short  short4v __attribute__((ext_vector_type(4)));
typedef short  short8  __attribute__((ext_vector_type(8)));
typedef float  floatx4 __attribute__((ext_vector_type(4)));
typedef unsigned uint4v __attribute__((ext_vector_type(4)));

// fp32 -> bf16 (RNE)
__device__ inline short f2bf(float f) {
  unsigned u = __builtin_bit_cast(unsigned, f);
  u = (u + 0x7FFF + ((u >> 16) & 1)) >> 16;
  return (short)u;
}

// pack two f32 -> dword of two bf16 (truncation) in ONE v_perm_b32
__device__ inline unsigned pack_trunc(float lo, float hi) {
  return __builtin_amdgcn_perm(__builtin_bit_cast(unsigned, hi),
                               __builtin_bit_cast(unsigned, lo), 0x07060302u);
}

// async 16B global -> LDS (lds base wave-uniform; HW adds lane*16)
__device__ inline void async_copy16(const short* g, short* l) {
  __builtin_amdgcn_global_load_lds(
      (const __attribute__((address_space(1))) unsigned int*)g,
      (__attribute__((address_space(3))) unsigned int*)l, 16, 0, 0);
}

// ---------------------------------------------------------------------------
// Mega prep: weight transposes (bf16 B^T pack), bias pack, x -> bf16
// ---------------------------------------------------------------------------
__global__ __launch_bounds__(256)
void prep_kernel(const float* __restrict__ x,  const float* __restrict__ Wq,
                 const float* __restrict__ Wk, const float* __restrict__ Wv,
                 const float* __restrict__ Wo, const float* __restrict__ bq,
                 const float* __restrict__ bk, const float* __restrict__ bv,
                 short* __restrict__ xb, short* __restrict__ Wqkv_t,
                 short* __restrict__ Wo_t, float* __restrict__ bqkv) {
  const int id = blockIdx.x;
  const int t  = threadIdx.x;
  if (id < 544) {
    __shared__ short Ts[64 * 72];
    const float* src; short* dst; int N, off, tile;
    if (id < 256)      { src = Wq; dst = Wqkv_t; N = 1024; off = 0;    tile = id; }
    else if (id < 272) { src = Wk; dst = Wqkv_t; N = 64;   off = 1024; tile = id - 256; }
    else if (id < 288) { src = Wv; dst = Wqkv_t; N = 64;   off = 1088; tile = id - 272; }
    else               { src = Wo; dst = Wo_t;   N = 1024; off = 0;    tile = id - 288; }
    const int k0 = (N == 1024) ? (tile & 15) * 64 : tile * 64;
    const int n0 = (N == 1024) ? (tile >> 4) * 64 : 0;
    {
      const int r = t >> 2, c = (t & 3) * 16;
      const float* s = src + (size_t)(k0 + r) * N + n0 + c;
#pragma unroll
      for (int j = 0; j < 16; j += 4) {
        float4 v = *reinterpret_cast<const float4*>(s + j);
        Ts[r * 72 + c + j + 0] = f2bf(v.x); Ts[r * 72 + c + j + 1] = f2bf(v.y);
        Ts[r * 72 + c + j + 2] = f2bf(v.z); Ts[r * 72 + c + j + 3] = f2bf(v.w);
      }
    }
    __syncthreads();
    {
      const int n = t >> 2, kc = (t & 3) * 16;
      short8 o0, o1;
#pragma unroll
      for (int j = 0; j < 8; ++j) o0[j] = Ts[(kc + j) * 72 + n];
#pragma unroll
      for (int j = 0; j < 8; ++j) o1[j] = Ts[(kc + 8 + j) * 72 + n];
      short* d = dst + (size_t)(off + n0 + n) * 1024 + k0 + kc;
      *reinterpret_cast<short8*>(d)     = o0;
      *reinterpret_cast<short8*>(d + 8) = o1;
    }
  } else if (id < 549) {
    const int i = (id - 544) * 256 + t;
    if (i < 1024)      bqkv[i] = bq[i];
    else if (i < 1088) bqkv[i] = bk[i - 1024];
    else if (i < 1152) bqkv[i] = bv[i - 1088];
  } else {
    const int i = ((id - 549) * 256 + t) * 8;
    if (i < MROWS * D_MODEL) {
      float4 a = *reinterpret_cast<const float4*>(x + i);
      float4 b = *reinterpret_cast<const float4*>(x + i + 4);
      short8 o;
      o[0] = f2bf(a.x); o[1] = f2bf(a.y); o[2] = f2bf(a.z); o[3] = f2bf(a.w);
      o[4] = f2bf(b.x); o[5] = f2bf(b.y); o[6] = f2bf(b.z); o[7] = f2bf(b.w);
      *reinterpret_cast<short8*>(xb + i) = o;
    }
  }
}

// ---------------------------------------------------------------------------
// bf16 MFMA GEMM, 128x64 tile, BK=64, PING-PONG double-buffered staging
// (R5 build — best measured; 128x128/512thr was slower, R8).
// SCALE_N: cols < SCALE_N scaled by 0.125*log2(e) (folds attention scale).
// VT_FUSE: cols in [1088,1152) additionally written transposed to Vtg.
// ---------------------------------------------------------------------------
template<bool OUT_BF16, int SCALE_N, bool VT_FUSE>
__global__ __launch_bounds__(256)
void gemm_mfma_bt(const short* __restrict__ A, const short* __restrict__ Bt,
                  const float* __restrict__ bias, void* __restrict__ Cout,
                  short* __restrict__ Vtg, int M, int N, int K) {
  __shared__ short As[2][128 * 64];   // 2 x 16 KB
  __shared__ short Bs[2][64 * 64];    // 2 x  8 KB   (total 48 KB -> 3/CU)
  const int t    = threadIdx.x;
  const int w    = t >> 6;
  const int lane = t & 63;
  const int quad = lane >> 4;
  const int l16  = lane & 15;
  const int bm   = blockIdx.x * 128;
  const int bn   = blockIdx.y * 64;
  const int wm   = (w >> 1) * 64;
  const int wn   = (w & 1) * 32;

  const int srow = t >> 3;
  const int cc   = ((t & 7) ^ (srow & 7)) * 8;
  const short* gA = A  + (size_t)(bm + srow) * K + cc;
  const short* gB = Bt + (size_t)(bn + srow) * K + cc;

  floatx4 acc[4][2];
#pragma unroll
  for (int i = 0; i < 4; ++i)
#pragma unroll
    for (int j = 0; j < 2; ++j) acc[i][j] = (floatx4){0.f, 0.f, 0.f, 0.f};

  const int xr = l16 & 7;

  // prologue: stage K-step 0 into buffer 0
  async_copy16(gA, &As[0][t * 8]);
  async_copy16(gA + (size_t)32 * K, &As[0][t * 8 + 2048]);
  async_copy16(gA + (size_t)64 * K, &As[0][t * 8 + 4096]);
  async_copy16(gA + (size_t)96 * K, &As[0][t * 8 + 6144]);
  async_copy16(gB, &Bs[0][t * 8]);
  async_copy16(gB + (size_t)32 * K, &Bs[0][t * 8 + 2048]);

  int cur = 0;
  for (int k0 = 0; k0 < K; k0 += 64) {
    asm volatile("s_waitcnt vmcnt(0)" ::: "memory");
    __builtin_amdgcn_s_barrier();
    __builtin_amdgcn_sched_barrier(0);

    if (k0 + 64 < K) {
      const int nb = cur ^ 1;
      const int kn = k0 + 64;
      async_copy16(gA + kn, &As[nb][t * 8]);
      async_copy16(gA + (size_t)32 * K + kn, &As[nb][t * 8 + 2048]);
      async_copy16(gA + (size_t)64 * K + kn, &As[nb][t * 8 + 4096]);
      async_copy16(gA + (size_t)96 * K + kn, &As[nb][t * 8 + 6144]);
      async_copy16(gB + kn, &Bs[nb][t * 8]);
      async_copy16(gB + (size_t)32 * K + kn, &Bs[nb][t * 8 + 2048]);
    }
    __builtin_amdgcn_sched_barrier(0);   // pin prefetch issue before compute

    const short* Ac = As[cur];
    const short* Bc = Bs[cur];
    short8 fa0[4], fa1[4], fb0[2], fb1[2];
#pragma unroll
    for (int mi = 0; mi < 4; ++mi) {
      const int row = wm + mi * 16 + l16;
      fa0[mi] = *reinterpret_cast<const short8*>(&Ac[row * 64 + (quad ^ xr) * 8]);
      fa1[mi] = *reinterpret_cast<const short8*>(&Ac[row * 64 + ((4 + quad) ^ xr) * 8]);
    }
#pragma unroll
    for (int ni = 0; ni < 2; ++ni) {
      const int row = wn + ni * 16 + l16;
      fb0[ni] = *reinterpret_cast<const short8*>(&Bc[row * 64 + (quad ^ xr) * 8]);
      fb1[ni] = *reinterpret_cast<const short8*>(&Bc[row * 64 + ((4 + quad) ^ xr) * 8]);
    }
#pragma unroll
    for (int mi = 0; mi < 4; ++mi)
#pragma unroll
      for (int ni = 0; ni < 2; ++ni) {
        acc[mi][ni] = __builtin_amdgcn_mfma_f32_16x16x32_bf16(fa0[mi], fb0[ni], acc[mi][ni], 0, 0, 0);
        acc[mi][ni] = __builtin_amdgcn_mfma_f32_16x16x32_bf16(fa1[mi], fb1[ni], acc[mi][ni], 0, 0, 0);
      }
    cur ^= 1;
  }

#pragma unroll
  for (int ni = 0; ni < 2; ++ni) {
    const int col = bn + wn + ni * 16 + l16;
    const float bs = bias[col];
    const float sc = (col < SCALE_N) ? 0.18033688f : 1.0f;  // 0.125*log2(e)
#pragma unroll
    for (int mi = 0; mi < 4; ++mi) {
      const int row = bm + wm + mi * 16 + quad * 4;
      short4v vt4;
#pragma unroll
      for (int r = 0; r < 4; ++r) {
        const float v = (acc[mi][ni][r] + bs) * sc;
        if (OUT_BF16) {
          const short bv16 = f2bf(v);
          ((short*)Cout)[(size_t)(row + r) * N + col] = bv16;
          if (VT_FUSE) vt4[r] = bv16;
        } else {
          ((float*)Cout)[(size_t)(row + r) * N + col] = v;
        }
      }
      if (VT_FUSE && col >= 1088) {
        const int d = col - 1088;
        const int b = row >> 11, s = row & 2047;
        *reinterpret_cast<short4v*>(&Vtg[(size_t)(b * 64 + d) * SEQ + s]) = vt4;
      }
    }
  }
}

// ---------------------------------------------------------------------------
// bf16 flash MQA — in-register P, QBLK=128, 128-key tiles per barrier,
// V stored as TWO R5-style [64][64] tiles (V0 keys 0-63, V1 keys 64-127).
//  R9's single V^T[64][128] layout (256B row stride) re-introduced 2.1M
//  bank conflicts and cost 7us; the [64][64] per-half read pattern measured
//  ZERO conflicts for six rounds. Only the base offset differs per half.
//  - per buffer (32KB): K[128][64] @0 | V0[64][64] @8192 | V1[64][64] @12288
//  - one vmcnt(0)+s_barrier per 128 keys (half the sync events of R5)
//  - K rows PERMUTED at staging: row r holds key
//      key(r) = (r&96) + ((r>>4)&1)*4 + ((r>>2)&3)*8 + (r&3)
//    -> QK^T output lane (l16,quad) holds keys half*64+quad*8..+7:
//    PV A-fragment is LANE-LOCAL, P never touches LDS.
//  - 64KB LDS -> 2 blocks/CU; grid 512 = 256 CU x 2, no split, no combine:
//    final softmax divide + bf16 Att written here.
// ---------------------------------------------------------------------------
__global__ __launch_bounds__(256, 2)
void mqa_flash_bf16(const short* __restrict__ QKV, const short* __restrict__ Vtg,
                    short* __restrict__ Att) {
  const int bh   = blockIdx.y;
  const int b    = bh >> 4;
  const int h    = bh & 15;
  const int s0   = blockIdx.x * 128;
  const int t    = threadIdx.x;
  const int w    = t >> 6;
  const int lane = t & 63;
  const int quad = lane >> 4;
  const int l16  = lane & 15;

  __shared__ short KVs[2][16384];  // K[128][64] | V0[64][64] | V1[64][64]

  // Q B-frags (pre-scaled in GEMM epilogue)
  short8 aq[2][2];
#pragma unroll
  for (int st = 0; st < 2; ++st) {
    const short* qrow = &QKV[(size_t)(b * SEQ + s0 + w * 32 + st * 16 + l16) * NQKV + h * HD];
    aq[st][0] = *reinterpret_cast<const short8*>(qrow + quad * 8);
    aq[st][1] = *reinterpret_cast<const short8*>(qrow + 32 + quad * 8);
  }

  floatx4 oacc[2][4];
  floatx4 lacc[2];
#pragma unroll
  for (int st = 0; st < 2; ++st) {
    lacc[st] = (floatx4){0.f, 0.f, 0.f, 0.f};
#pragma unroll
    for (int dg = 0; dg < 4; ++dg) oacc[st][dg] = (floatx4){0.f, 0.f, 0.f, 0.f};
  }

  short8 ones;
#pragma unroll
  for (int j = 0; j < 8; ++j) ones[j] = (short)0x3F80;  // bf16 1.0

  // staging sources (XOR-swizzled 16B chunks), R5-proven geometry:
  // srow = t>>3 (0..31), chunk (t&7)^(srow&7).
  // K row is PERMUTED key row krow; key(r+32j)=key(r)+32j -> +32j*NQKV offs.
  const int srow = t >> 3;
  const int cc   = ((t & 7) ^ (srow & 7)) * 8;
  const int krow = ((srow >> 4) & 1) * 4 + ((srow >> 2) & 3) * 8 + (srow & 3);
  const short* gK = QKV + (size_t)(b * SEQ + krow) * NQKV + 1024 + cc;
  const short* gV = Vtg + (size_t)(b * 64 + srow) * SEQ + cc;   // d-row srow

  const int xr = l16 & 7;

#define STAGE(BUF)                                                     \
  {                                                                    \
    short* lK  = KVs[BUF] + w * 512;                                   \
    short* lV0 = KVs[BUF] + 8192  + w * 512;                           \
    short* lV1 = KVs[BUF] + 12288 + w * 512;                           \
    async_copy16(gK, lK);                                              \
    async_copy16(gK + (size_t)32 * NQKV, lK + 2048);                   \
    async_copy16(gK + (size_t)64 * NQKV, lK + 4096);                   \
    async_copy16(gK + (size_t)96 * NQKV, lK + 6144);                   \
    async_copy16(gV, lV0);                                             \
    async_copy16(gV + (size_t)32 * SEQ, lV0 + 2048);                   \
    async_copy16(gV + 64, lV1);                                        \
    async_copy16(gV + (size_t)32 * SEQ + 64, lV1 + 2048);              \
    gK += (size_t)128 * NQKV;                                          \
    gV += 128;                                                         \
  }

  // prologue: stage tile 0 (128 keys) into buf0
  STAGE(0)

  const int NT = SEQ / 128;   // 16
  int cur = 0;

  for (int it = 0; it < NT; ++it) {
    // buf[cur]'s DMA (issued last iter, hidden under 128 keys of compute)
    asm volatile("s_waitcnt vmcnt(0)" ::: "memory");
    __builtin_amdgcn_s_barrier();
    __builtin_amdgcn_sched_barrier(0);

    // prefetch next 128-key tile into the other buffer (all waves' reads of
    // it completed before they arrived at the barrier above)
    if (it + 1 < NT) STAGE(cur ^ 1)
    __builtin_amdgcn_sched_barrier(0);   // pin prefetch issue before compute

#pragma unroll
    for (int half = 0; half < 2; ++half) {
      const short* Ks = KVs[cur] + half * 4096;           // K rows half*64..
      const short* Vt = KVs[cur] + 8192 + half * 4096;    // V-half [64][64]

      short8 kb[4][2], vb[4][2];
#pragma unroll
      for (int kg = 0; kg < 4; ++kg) {
        kb[kg][0] = *reinterpret_cast<const short8*>(&Ks[(kg * 16 + l16) * 64 + (quad ^ xr) * 8]);
        kb[kg][1] = *reinterpret_cast<const short8*>(&Ks[(kg * 16 + l16) * 64 + ((4 + quad) ^ xr) * 8]);
      }
#pragma unroll
      for (int dg = 0; dg < 4; ++dg) {
        vb[dg][0] = *reinterpret_cast<const short8*>(&Vt[(dg * 16 + l16) * 64 + (quad ^ xr) * 8]);
        vb[dg][1] = *reinterpret_cast<const short8*>(&Vt[(dg * 16 + l16) * 64 + ((4 + quad) ^ xr) * 8]);
      }

#pragma unroll
      for (int st = 0; st < 2; ++st) {
        // S^T = K·Q^T over permuted key rows; p = exp2(s)
        floatx4 s4[4];
#pragma unroll
        for (int kg = 0; kg < 4; ++kg) {
          s4[kg] = (floatx4){0.f, 0.f, 0.f, 0.f};
          s4[kg] = __builtin_amdgcn_mfma_f32_16x16x32_bf16(kb[kg][0], aq[st][0], s4[kg], 0, 0, 0);
          s4[kg] = __builtin_amdgcn_mfma_f32_16x16x32_bf16(kb[kg][1], aq[st][1], s4[kg], 0, 0, 0);
        }
        // lane-local P -> bf16 A-frags (keys quad*8..+7 within half)
        unsigned pk[8];
#pragma unroll
        for (int kg = 0; kg < 4; ++kg) {
          const float p0 = __builtin_exp2f(s4[kg][0]);
          const float p1 = __builtin_exp2f(s4[kg][1]);
          const float p2 = __builtin_exp2f(s4[kg][2]);
          const float p3 = __builtin_exp2f(s4[kg][3]);
          pk[kg * 2 + 0] = pack_trunc(p0, p1);
          pk[kg * 2 + 1] = pack_trunc(p2, p3);
        }
        const uint4v u0 = (uint4v){pk[0], pk[1], pk[2], pk[3]};
        const uint4v u1 = (uint4v){pk[4], pk[5], pk[6], pk[7]};
        const short8 ap0 = __builtin_bit_cast(short8, u0);
        const short8 ap1 = __builtin_bit_cast(short8, u1);

        // O += P·V ; l += P·ones
        __builtin_amdgcn_s_setprio(1);
        lacc[st] = __builtin_amdgcn_mfma_f32_16x16x32_bf16(ap0, ones, lacc[st], 0, 0, 0);
        lacc[st] = __builtin_amdgcn_mfma_f32_16x16x32_bf16(ap1, ones, lacc[st], 0, 0, 0);
#pragma unroll
        for (int dg = 0; dg < 4; ++dg) {
          oacc[st][dg] = __builtin_amdgcn_mfma_f32_16x16x32_bf16(ap0, vb[dg][0], oacc[st][dg], 0, 0, 0);
          oacc[st][dg] = __builtin_amdgcn_mfma_f32_16x16x32_bf16(ap1, vb[dg][1], oacc[st][dg], 0, 0, 0);
        }
        __builtin_amdgcn_s_setprio(0);
      }
    }
    cur ^= 1;
  }
#undef STAGE

  // epilogue: final softmax divide, write bf16 Att directly
  short* At = Att + (size_t)b * SEQ * D_MODEL + h * HD;
#pragma unroll
  for (int st = 0; st < 2; ++st) {
#pragma unroll
    for (int rg = 0; rg < 4; ++rg) {
      const int q = s0 + w * 32 + st * 16 + quad * 4 + rg;
      const float inv = 1.0f / lacc[st][rg];
      short* dst = At + (size_t)q * D_MODEL + l16;
#pragma unroll
      for (int dg = 0; dg < 4; ++dg) dst[dg * 16] = f2bf(oacc[st][dg][rg] * inv);
    }
  }
}

// ---------------------------------------------------------------------------
extern "C" void kernel_launch(void* const* d_in, const int* in_sizes, int n_in,
                              void* d_out, int out_size, void* d_ws, size_t ws_size,
                              hipStream_t stream) {
  const float* x  = (const float*)d_in[0];
  const float* Wq = (const float*)d_in[1];
  const float* bq = (const float*)d_in[2];
  const float* Wk = (const float*)d_in[3];
  const float* bk = (const float*)d_in[4];
  const float* Wv = (const float*)d_in[5];
  const float* bv = (const float*)d_in[6];
  const float* Wo = (const float*)d_in[7];
  const float* bo = (const float*)d_in[8];
  float* out = (float*)d_out;

  short* Wqkv_t = (short*)d_ws;                              // 1152*1024
  short* Wo_t   = Wqkv_t + (size_t)NQKV * D_MODEL;           // 1024*1024
  short* xb     = Wo_t + (size_t)D_MODEL * D_MODEL;          // 4096*1024
  short* QKV    = xb + (size_t)MROWS * D_MODEL;              // 4096*1152
  short* Att    = QKV + (size_t)MROWS * NQKV;                // 4096*1024
  short* Vtg    = Att + (size_t)MROWS * D_MODEL;             // 2*64*2048
  float* bqkv   = (float*)(Vtg + (size_t)BATCH * HD * SEQ);  // 1152

  prep_kernel<<<2597, 256, 0, stream>>>(x, Wq, Wk, Wv, Wo, bq, bk, bv,
                                        xb, Wqkv_t, Wo_t, bqkv);

  // QKV projection; Q cols pre-scaled; V cols also written transposed (Vtg)
  gemm_mfma_bt<true, 1024, true><<<dim3(MROWS / 128, NQKV / 64), 256, 0, stream>>>(
      xb, Wqkv_t, bqkv, QKV, Vtg, MROWS, NQKV, D_MODEL);

  mqa_flash_bf16<<<dim3(SEQ / 128, BATCH * NHEADS), 256, 0, stream>>>(
      QKV, Vtg, Att);

  gemm_mfma_bt<false, 0, false><<<dim3(MROWS / 128, D_MODEL / 64), 256, 0, stream>>>(
      Att, Wo_t, bo, out, nullptr, MROWS, D_MODEL, D_MODEL);
}